// Round 1
// baseline (2112.167 us; speedup 1.0000x reference)
//
#include <hip/hip_runtime.h>
#include <math.h>

// ---------------------------------------------------------------------------
// VQ-VAE forward, fp32 baseline.
//   conv1: x(32,3,256,256) --k4 s2 p1--> z1(32,64,128,128), relu
//   conv2: z1 --k4 s2 p1--> ze(32,64,64,64), relu
//   vq:    rows = ze.flat reshaped (131072, 64); 512 codes; zq = cb[argmin]
//   deconv1: zq --k4 s2 p1 transpose--> h(32,64,128,128), relu
//   deconv2: h --k4 s2 p1 transpose--> xr(32,3,256,256), sigmoid
// ws: z1/h buffer (33,554,432 f) + ze (8,388,608 f) = 167.8 MB
// ---------------------------------------------------------------------------

__global__ __launch_bounds__(256) void k_conv1(const float* __restrict__ x,
                                               const float* __restrict__ w1,
                                               const float* __restrict__ b1,
                                               float* __restrict__ z1) {
  __shared__ float sW[3 * 16 * 64];   // [c][t=kh*4+kw][oc]
  __shared__ float sB[64];
  __shared__ float sIn[3 * 34 * 34];  // [c][r][col]
  const int tid = threadIdx.x;

  for (int i = tid; i < 3072; i += 256) {
    int oc = i & 63, t = (i >> 6) & 15, c = i >> 10;
    sW[i] = w1[(oc * 3 + c) * 16 + t];   // w1: (oc=64, c=3, kh, kw)
  }
  if (tid < 64) sB[tid] = b1[tid];

  const int b = blockIdx.x;
  const int n = b >> 6;
  const int tile = b & 63;
  const int tr = tile >> 3, tc = tile & 7;
  const int oh0 = tr * 16, ow0 = tc * 16;
  const int ih_base = oh0 * 2 - 1, iw_base = ow0 * 2 - 1;

  for (int i = tid; i < 3468; i += 256) {
    int c = i / 1156;
    int rem = i - c * 1156;
    int r = rem / 34;
    int col = rem - r * 34;
    int ih = ih_base + r, iw = iw_base + col;
    float v = 0.f;
    if ((unsigned)ih < 256u && (unsigned)iw < 256u)
      v = x[((n * 3 + c) * 256 + ih) * 256 + iw];
    sIn[i] = v;
  }
  __syncthreads();

  const int ty = tid >> 4, tx = tid & 15;
  float acc[64];
#pragma unroll
  for (int j = 0; j < 64; ++j) acc[j] = sB[j];

  for (int c = 0; c < 3; ++c) {
    for (int t = 0; t < 16; ++t) {
      int kh = t >> 2, kw = t & 3;
      float v = sIn[c * 1156 + (2 * ty + kh) * 34 + (2 * tx + kw)];
      const float4* wp = (const float4*)&sW[(c * 16 + t) * 64];
#pragma unroll
      for (int j = 0; j < 16; ++j) {
        float4 w4 = wp[j];
        acc[4 * j + 0] += v * w4.x;
        acc[4 * j + 1] += v * w4.y;
        acc[4 * j + 2] += v * w4.z;
        acc[4 * j + 3] += v * w4.w;
      }
    }
  }

  const int oh = oh0 + ty, ow = ow0 + tx;
#pragma unroll
  for (int j = 0; j < 64; ++j) {
    float r = acc[j];
    r = r > 0.f ? r : 0.f;
    z1[((n * 64 + j) * 128 + oh) * 128 + ow] = r;
  }
}

__global__ __launch_bounds__(256) void k_conv2(const float* __restrict__ z1,
                                               const float* __restrict__ w2,
                                               const float* __restrict__ b2,
                                               float* __restrict__ ze) {
  __shared__ float sIn[4 * 34 * 34];  // 4624
  __shared__ float sW[4 * 16 * 64];   // 4096, [c][t][oc]
  const int tid = threadIdx.x;
  const int b = blockIdx.x;
  const int n = b >> 4;
  const int tile = b & 15;
  const int tr = tile >> 2, tc = tile & 3;
  const int oh0 = tr * 16, ow0 = tc * 16;
  const int ih_base = oh0 * 2 - 1, iw_base = ow0 * 2 - 1;
  const int ty = tid >> 4, tx = tid & 15;

  float acc[64];
#pragma unroll
  for (int j = 0; j < 64; ++j) acc[j] = 0.f;

  for (int c0 = 0; c0 < 64; c0 += 4) {
    __syncthreads();
    for (int i = tid; i < 4624; i += 256) {
      int c = i / 1156;
      int rem = i - c * 1156;
      int r = rem / 34;
      int col = rem - r * 34;
      int ih = ih_base + r, iw = iw_base + col;
      float v = 0.f;
      if ((unsigned)ih < 128u && (unsigned)iw < 128u)
        v = z1[((n * 64 + c0 + c) * 128 + ih) * 128 + iw];
      sIn[i] = v;
    }
    for (int i = tid; i < 4096; i += 256) {
      int oc = i & 63, t = (i >> 6) & 15, c = i >> 10;
      sW[i] = w2[(oc * 64 + c0 + c) * 16 + t];   // w2: (oc=64, c=64, kh, kw)
    }
    __syncthreads();

    for (int c = 0; c < 4; ++c) {
      for (int t = 0; t < 16; ++t) {
        int kh = t >> 2, kw = t & 3;
        float v = sIn[c * 1156 + (2 * ty + kh) * 34 + (2 * tx + kw)];
        const float4* wp = (const float4*)&sW[(c * 16 + t) * 64];
#pragma unroll
        for (int j = 0; j < 16; ++j) {
          float4 w4 = wp[j];
          acc[4 * j + 0] += v * w4.x;
          acc[4 * j + 1] += v * w4.y;
          acc[4 * j + 2] += v * w4.z;
          acc[4 * j + 3] += v * w4.w;
        }
      }
    }
  }

  const int oh = oh0 + ty, ow = ow0 + tx;
#pragma unroll
  for (int j = 0; j < 64; ++j) {
    float r = acc[j] + b2[j];
    r = r > 0.f ? r : 0.f;
    ze[((n * 64 + j) * 64 + oh) * 64 + ow] = r;
  }
}

__global__ __launch_bounds__(256) void k_vq(const float* __restrict__ ze,
                                            const float* __restrict__ cb,
                                            float* __restrict__ zq) {
  __shared__ float sC[128 * 64];  // 32 KB: 128 codes per pass
  __shared__ float sN[128];
  const int tid = threadIdx.x;
  const int row0 = blockIdx.x * 512 + tid;
  const int row1 = row0 + 256;

  float4 za[16], zb[16];
  const float4* p0 = (const float4*)(ze + row0 * 64);
  const float4* p1 = (const float4*)(ze + row1 * 64);
#pragma unroll
  for (int j = 0; j < 16; ++j) {
    za[j] = p0[j];
    zb[j] = p1[j];
  }

  float best0 = 3.4e38f, best1 = 3.4e38f;
  int bi0 = 0, bi1 = 0;

  for (int p = 0; p < 4; ++p) {
    __syncthreads();
    for (int i = tid; i < 8192; i += 256) sC[i] = cb[p * 8192 + i];
    __syncthreads();
    if (tid < 128) {
      float s = 0.f;
      const float* cp = &sC[tid * 64];
#pragma unroll
      for (int j = 0; j < 64; ++j) s += cp[j] * cp[j];
      sN[tid] = s;
    }
    __syncthreads();

    for (int k = 0; k < 128; ++k) {
      const float4* cp = (const float4*)&sC[k * 64];
      float4 d0 = make_float4(0.f, 0.f, 0.f, 0.f);
      float4 d1 = make_float4(0.f, 0.f, 0.f, 0.f);
#pragma unroll
      for (int j = 0; j < 16; ++j) {
        float4 c4 = cp[j];
        d0.x += za[j].x * c4.x; d0.y += za[j].y * c4.y;
        d0.z += za[j].z * c4.z; d0.w += za[j].w * c4.w;
        d1.x += zb[j].x * c4.x; d1.y += zb[j].y * c4.y;
        d1.z += zb[j].z * c4.z; d1.w += zb[j].w * c4.w;
      }
      float dot0 = (d0.x + d0.y) + (d0.z + d0.w);
      float dot1 = (d1.x + d1.y) + (d1.z + d1.w);
      float nk = sN[k];
      float m0 = nk - 2.f * dot0;
      float m1 = nk - 2.f * dot1;
      int ki = p * 128 + k;
      if (m0 < best0) { best0 = m0; bi0 = ki; }
      if (m1 < best1) { best1 = m1; bi1 = ki; }
    }
  }

  const float4* s0 = (const float4*)(cb + bi0 * 64);
  const float4* s1 = (const float4*)(cb + bi1 * 64);
  float4* q0 = (float4*)(zq + row0 * 64);
  float4* q1 = (float4*)(zq + row1 * 64);
#pragma unroll
  for (int j = 0; j < 16; ++j) {
    q0[j] = s0[j];
    q1[j] = s1[j];
  }
}

__global__ __launch_bounds__(256) void k_deconv1(const float* __restrict__ zq,
                                                 const float* __restrict__ dw1,
                                                 const float* __restrict__ db1,
                                                 float* __restrict__ h) {
  __shared__ float sIn[8 * 10 * 10];  // 800
  __shared__ float sW[8 * 16 * 64];   // 8192, [c][t][oc]
  const int tid = threadIdx.x;
  const int b = blockIdx.x;
  const int n = b >> 6;
  const int tile = b & 63;
  const int tr = tile >> 3, tc = tile & 7;
  const int oh0 = tr * 16, ow0 = tc * 16;
  const int ih0 = (oh0 >> 1) - 1, iw0 = (ow0 >> 1) - 1;
  const int ty = tid >> 4, tx = tid & 15;

  float acc[64];
#pragma unroll
  for (int j = 0; j < 64; ++j) acc[j] = 0.f;

  // ConvTranspose taps: oh = 2*ih - 1 + kh  =>  kh = (1 - oh%2) + 2a
  const int ph = ty & 1, pw = tx & 1;
  int kh[2], ihL[2], kw[2], iwL[2];
#pragma unroll
  for (int a = 0; a < 2; ++a) {
    kh[a] = 1 - ph + 2 * a;
    ihL[a] = ((ty + 1 - kh[a]) >> 1) + 1;  // ih - ih0 (local, in [0,10))
    kw[a] = 1 - pw + 2 * a;
    iwL[a] = ((tx + 1 - kw[a]) >> 1) + 1;
  }

  for (int c0 = 0; c0 < 64; c0 += 8) {
    __syncthreads();
    for (int i = tid; i < 800; i += 256) {
      int c = i / 100;
      int rem = i - c * 100;
      int r = rem / 10;
      int col = rem - r * 10;
      int ih = ih0 + r, iw = iw0 + col;
      float v = 0.f;
      if ((unsigned)ih < 64u && (unsigned)iw < 64u)
        v = zq[((n * 64 + c0 + c) * 64 + ih) * 64 + iw];
      sIn[i] = v;
    }
    for (int i = tid; i < 8192; i += 256) {
      int oc = i & 63, t = (i >> 6) & 15, c = i >> 10;
      sW[i] = dw1[((c0 + c) * 64 + oc) * 16 + t];  // dw1: (c=64, oc=64, kh, kw)
    }
    __syncthreads();

    for (int c = 0; c < 8; ++c) {
#pragma unroll
      for (int a = 0; a < 2; ++a) {
#pragma unroll
        for (int bb = 0; bb < 2; ++bb) {
          float v = sIn[c * 100 + ihL[a] * 10 + iwL[bb]];
          int t = kh[a] * 4 + kw[bb];
          const float4* wp = (const float4*)&sW[(c * 16 + t) * 64];
#pragma unroll
          for (int j = 0; j < 16; ++j) {
            float4 w4 = wp[j];
            acc[4 * j + 0] += v * w4.x;
            acc[4 * j + 1] += v * w4.y;
            acc[4 * j + 2] += v * w4.z;
            acc[4 * j + 3] += v * w4.w;
          }
        }
      }
    }
  }

  const int oh = oh0 + ty, ow = ow0 + tx;
#pragma unroll
  for (int j = 0; j < 64; ++j) {
    float r = acc[j] + db1[j];
    r = r > 0.f ? r : 0.f;
    h[((n * 64 + j) * 128 + oh) * 128 + ow] = r;
  }
}

__global__ __launch_bounds__(256) void k_deconv2(const float* __restrict__ h,
                                                 const float* __restrict__ dw2,
                                                 const float* __restrict__ db2,
                                                 float* __restrict__ xr) {
  __shared__ float sIn[8 * 10 * 10];
  __shared__ float sW[3072];  // dw2 as-is: (c=64, oc=3, kh, kw)
  __shared__ float sB[3];
  const int tid = threadIdx.x;
  for (int i = tid; i < 3072; i += 256) sW[i] = dw2[i];
  if (tid < 3) sB[tid] = db2[tid];

  const int b = blockIdx.x;
  const int n = b >> 8;
  const int tile = b & 255;
  const int tr = tile >> 4, tc = tile & 15;
  const int oh0 = tr * 16, ow0 = tc * 16;
  const int ih0 = (oh0 >> 1) - 1, iw0 = (ow0 >> 1) - 1;
  const int ty = tid >> 4, tx = tid & 15;

  const int ph = ty & 1, pw = tx & 1;
  int kh[2], ihL[2], kw[2], iwL[2];
#pragma unroll
  for (int a = 0; a < 2; ++a) {
    kh[a] = 1 - ph + 2 * a;
    ihL[a] = ((ty + 1 - kh[a]) >> 1) + 1;
    kw[a] = 1 - pw + 2 * a;
    iwL[a] = ((tx + 1 - kw[a]) >> 1) + 1;
  }

  float a0 = 0.f, a1 = 0.f, a2 = 0.f;

  for (int c0 = 0; c0 < 64; c0 += 8) {
    __syncthreads();
    for (int i = tid; i < 800; i += 256) {
      int c = i / 100;
      int rem = i - c * 100;
      int r = rem / 10;
      int col = rem - r * 10;
      int ih = ih0 + r, iw = iw0 + col;
      float v = 0.f;
      if ((unsigned)ih < 128u && (unsigned)iw < 128u)
        v = h[((n * 64 + c0 + c) * 128 + ih) * 128 + iw];
      sIn[i] = v;
    }
    __syncthreads();

    for (int c = 0; c < 8; ++c) {
#pragma unroll
      for (int a = 0; a < 2; ++a) {
#pragma unroll
        for (int bb = 0; bb < 2; ++bb) {
          float v = sIn[c * 100 + ihL[a] * 10 + iwL[bb]];
          int t = kh[a] * 4 + kw[bb];
          int cg = c0 + c;
          a0 += v * sW[(cg * 3 + 0) * 16 + t];
          a1 += v * sW[(cg * 3 + 1) * 16 + t];
          a2 += v * sW[(cg * 3 + 2) * 16 + t];
        }
      }
    }
  }

  const int oh = oh0 + ty, ow = ow0 + tx;
  float v0 = 1.f / (1.f + expf(-(a0 + sB[0])));
  float v1 = 1.f / (1.f + expf(-(a1 + sB[1])));
  float v2 = 1.f / (1.f + expf(-(a2 + sB[2])));
  xr[((n * 3 + 0) * 256 + oh) * 256 + ow] = v0;
  xr[((n * 3 + 1) * 256 + oh) * 256 + ow] = v1;
  xr[((n * 3 + 2) * 256 + oh) * 256 + ow] = v2;
}

extern "C" void kernel_launch(void* const* d_in, const int* in_sizes, int n_in,
                              void* d_out, int out_size, void* d_ws, size_t ws_size,
                              hipStream_t stream) {
  (void)in_sizes; (void)n_in; (void)out_size; (void)ws_size;

  const float* x   = (const float*)d_in[0];
  const float* w1  = (const float*)d_in[1];
  const float* b1  = (const float*)d_in[2];
  const float* w2  = (const float*)d_in[3];
  const float* b2  = (const float*)d_in[4];
  const float* cb  = (const float*)d_in[5];
  const float* dw1 = (const float*)d_in[6];
  const float* db1 = (const float*)d_in[7];
  const float* dw2 = (const float*)d_in[8];
  const float* db2 = (const float*)d_in[9];

  float* ws = (float*)d_ws;
  float* z1 = ws;              // 33,554,432 floats; reused as h after VQ
  float* ze = ws + 33554432;   // 8,388,608 floats
  float* xr = (float*)d_out;                 // 6,291,456 floats
  float* zq = (float*)d_out + 6291456;       // 8,388,608 floats (output 1)

  k_conv1<<<2048, 256, 0, stream>>>(x, w1, b1, z1);
  k_conv2<<<512, 256, 0, stream>>>(z1, w2, b2, ze);
  k_vq<<<256, 256, 0, stream>>>(ze, cb, zq);
  k_deconv1<<<2048, 256, 0, stream>>>(zq, dw1, db1, z1 /* h */);
  k_deconv2<<<8192, 256, 0, stream>>>(z1 /* h */, dw2, db2, xr);
}

// Round 2
// 531.332 us; speedup vs baseline: 3.9752x; 3.9752x over previous
//
#include <hip/hip_runtime.h>
#include <math.h>

// ---------------------------------------------------------------------------
// VQ-VAE forward, bf16-MFMA version.
//   conv1 (fp32 VALU) -> z1T [n][128][128][64c] bf16
//   conv2 (MFMA)      -> ze  [n][64c][64][64]   bf16 (NCHW)
//   vq    (MFMA)      -> zq  fp32 d_out (exact cb rows) + zqT [n][64][64][64c] bf16
//   deconv1 (MFMA)    -> hT  [n][128][128][64c] bf16 (aliases z1T)
//   deconv2 (fp32)    -> xr  fp32 d_out
// ---------------------------------------------------------------------------

typedef __attribute__((ext_vector_type(8))) short short8;
typedef __attribute__((ext_vector_type(4))) short short4v;
typedef __attribute__((ext_vector_type(4))) float f32x4;

#define MFMA16(a, b, c) __builtin_amdgcn_mfma_f32_16x16x32_bf16((a), (b), (c), 0, 0, 0)

__device__ __forceinline__ short f2bf(float f) {
  union { float f; unsigned u; } x; x.f = f;
  unsigned r = (x.u + 0x7FFFu + ((x.u >> 16) & 1u)) >> 16;
  return (short)r;
}
__device__ __forceinline__ float bf2f(short s) {
  union { unsigned u; float f; } x;
  x.u = ((unsigned)(unsigned short)s) << 16;
  return x.f;
}

// ------------------------------ prep ---------------------------------------
// A2 [t16][oc64][c64]  = w2[oc][c][t]          (conv2 weights, bf16)
// AD1[p4][ab4][oc64][c64] = dw1[c][oc][kh][kw] (deconv1 parity weights, bf16)
// cbb[512][64] bf16, cnm[512] = ||cb_k||^2 fp32
__global__ __launch_bounds__(256) void k_prep(const float* __restrict__ w2,
                                              const float* __restrict__ dw1,
                                              const float* __restrict__ cb,
                                              short* __restrict__ A2,
                                              short* __restrict__ AD1,
                                              short* __restrict__ cbb,
                                              float* __restrict__ cnm) {
  int i = blockIdx.x * 256 + threadIdx.x;  // 0..65535
  {
    int t = i >> 12, oc = (i >> 6) & 63, c = i & 63;
    A2[i] = f2bf(w2[(oc * 64 + c) * 16 + t]);
  }
  {
    int p = i >> 14, ab = (i >> 12) & 3, oc = (i >> 6) & 63, c = i & 63;
    int kh = 1 - (p >> 1) + 2 * (ab >> 1);
    int kw = 1 - (p & 1) + 2 * (ab & 1);
    AD1[i] = f2bf(dw1[(c * 64 + oc) * 16 + kh * 4 + kw]);
  }
  if (i < 32768) cbb[i] = f2bf(cb[i]);
  if (i < 512) {
    float s = 0.f;
    for (int d = 0; d < 64; ++d) { float v = cb[i * 64 + d]; s += v * v; }
    cnm[i] = s;
  }
}

// ------------------------------ conv1 --------------------------------------
__global__ __launch_bounds__(256) void k_conv1(const float* __restrict__ x,
                                               const float* __restrict__ w1,
                                               const float* __restrict__ b1,
                                               short* __restrict__ z1T) {
  __shared__ float sW[3 * 16 * 64];
  __shared__ float sB[64];
  __shared__ float sIn[3 * 34 * 34];
  __shared__ short sOutC[256 * 72];
  const int tid = threadIdx.x;

  for (int i = tid; i < 3072; i += 256) {
    int oc = i & 63, t = (i >> 6) & 15, c = i >> 10;
    sW[i] = w1[(oc * 3 + c) * 16 + t];
  }
  if (tid < 64) sB[tid] = b1[tid];

  const int b = blockIdx.x;
  const int n = b >> 6;
  const int tile = b & 63;
  const int tr = tile >> 3, tc = tile & 7;
  const int oh0 = tr * 16, ow0 = tc * 16;
  const int ih_base = oh0 * 2 - 1, iw_base = ow0 * 2 - 1;

  for (int i = tid; i < 3468; i += 256) {
    int c = i / 1156;
    int rem = i - c * 1156;
    int r = rem / 34;
    int col = rem - r * 34;
    int ih = ih_base + r, iw = iw_base + col;
    float v = 0.f;
    if ((unsigned)ih < 256u && (unsigned)iw < 256u)
      v = x[((n * 3 + c) * 256 + ih) * 256 + iw];
    sIn[i] = v;
  }
  __syncthreads();

  const int ty = tid >> 4, tx = tid & 15;
  float acc[64];
#pragma unroll
  for (int j = 0; j < 64; ++j) acc[j] = sB[j];

  for (int c = 0; c < 3; ++c) {
    for (int t = 0; t < 16; ++t) {
      int kh = t >> 2, kw = t & 3;
      float v = sIn[c * 1156 + (2 * ty + kh) * 34 + (2 * tx + kw)];
      const float4* wp = (const float4*)&sW[(c * 16 + t) * 64];
#pragma unroll
      for (int j = 0; j < 16; ++j) {
        float4 w4 = wp[j];
        acc[4 * j + 0] += v * w4.x;
        acc[4 * j + 1] += v * w4.y;
        acc[4 * j + 2] += v * w4.z;
        acc[4 * j + 3] += v * w4.w;
      }
    }
  }

  // relu + bf16 -> LDS transpose -> coalesced z1T[n][oh][ow][c]
  const int sp = ty * 16 + tx;
#pragma unroll
  for (int kk = 0; kk < 8; ++kk) {
    short8 v;
#pragma unroll
    for (int t2 = 0; t2 < 8; ++t2) {
      float r = acc[8 * kk + t2];
      v[t2] = f2bf(r > 0.f ? r : 0.f);
    }
    *(short8*)&sOutC[sp * 72 + 8 * kk] = v;
  }
  __syncthreads();
  const int r = tid >> 4, jj = tid & 15;
#pragma unroll
  for (int it = 0; it < 8; ++it) {
    int chunk = jj + 16 * it;       // 0..127
    int owL = chunk >> 3, c8 = chunk & 7;
    short8 v = *(const short8*)&sOutC[(r * 16 + owL) * 72 + 8 * c8];
    *(short8*)(z1T + (((long)(n * 128 + oh0 + r) * 128) + ow0 + owL) * 64 + 8 * c8) = v;
  }
}

// ------------------------------ conv2 (MFMA) -------------------------------
// block: (n, oh-pair). 4 waves: wave = row*2 + mh; wave does m-tiles {2mh,2mh+1},
// all 4 n-tiles of its oh row. K = 2 c-passes x 16 taps x 32c.
__global__ __launch_bounds__(256) void k_conv2(const short* __restrict__ z1T,
                                               const short* __restrict__ A2,
                                               const float* __restrict__ b2,
                                               short* __restrict__ ze) {
  __shared__ char smemC[62400];   // slab [6][130][40c] bf16 (line-major x5) / sOut alias
  __shared__ float sB2c[64];
  short* slab = (short*)smemC;
  short* sOut = (short*)smemC;    // [2][64][68] bf16 after final barrier

  const int tid = threadIdx.x;
  if (tid < 64) sB2c[tid] = b2[tid];
  const int b = blockIdx.x;
  const int n = b >> 5;
  const int oh0 = (b & 31) * 2;
  const int w = tid >> 6, l = tid & 63;
  const int row = w >> 1, mh = w & 1;
  const int e = l & 15, kg = l >> 4;
  const int ih0 = 2 * oh0 - 1;

  f32x4 acc[2][4];
#pragma unroll
  for (int mi = 0; mi < 2; ++mi)
#pragma unroll
    for (int nt = 0; nt < 4; ++nt) acc[mi][nt] = (f32x4){0.f, 0.f, 0.f, 0.f};

  for (int p = 0; p < 2; ++p) {
    const int c0 = 32 * p;
    __syncthreads();
    for (int i = tid; i < 3120; i += 256) {   // 6*130*4 lines
      int r = i / 520;
      int rem = i - r * 520;
      int iwL = rem >> 2, li = rem & 3;
      int ih = ih0 + r, iw = iwL - 1;
      short8 v = {0, 0, 0, 0, 0, 0, 0, 0};
      if ((unsigned)ih < 128u && (unsigned)iw < 128u)
        v = *(const short8*)(z1T + (((long)(n * 128 + ih) * 128) + iw) * 64 + c0 + 8 * li);
      *(short8*)&slab[8 * ((r * 130 + iwL) * 5 + li)] = v;
    }
    __syncthreads();

    for (int t = 0; t < 16; ++t) {
      const int kh = t >> 2, kw = t & 3;
      const int rL = 2 * row + kh;
      short8 aF[2], bF[4];
#pragma unroll
      for (int mi = 0; mi < 2; ++mi)
        aF[mi] = *(const short8*)(A2 + ((t * 64 + 32 * mh + 16 * mi + e) * 64) + c0 + 8 * kg);
#pragma unroll
      for (int nt = 0; nt < 4; ++nt) {
        int iwL = 2 * (nt * 16 + e) + kw;
        bF[nt] = *(const short8*)&slab[8 * ((rL * 130 + iwL) * 5 + kg)];
      }
#pragma unroll
      for (int mi = 0; mi < 2; ++mi)
#pragma unroll
        for (int nt = 0; nt < 4; ++nt)
          acc[mi][nt] = MFMA16(aF[mi], bF[nt], acc[mi][nt]);
    }
  }

  // epilogue: bias+relu -> sOut[row][oc][ow] -> coalesced NCHW bf16 store
  __syncthreads();
#pragma unroll
  for (int mi = 0; mi < 2; ++mi)
#pragma unroll
    for (int nt = 0; nt < 4; ++nt)
#pragma unroll
      for (int rr = 0; rr < 4; ++rr) {
        int oc = 32 * mh + 16 * mi + 4 * kg + rr;
        float v = acc[mi][nt][rr] + sB2c[oc];
        sOut[(row * 64 + oc) * 68 + nt * 16 + e] = f2bf(v > 0.f ? v : 0.f);
      }
  __syncthreads();
  {
    int oc = 32 * mh + (l >> 1);
    int half = l & 1;
#pragma unroll
    for (int j = 0; j < 8; ++j) {
      short4v v = *(const short4v*)&sOut[(row * 64 + oc) * 68 + 32 * half + 4 * j];
      *(short4v*)(ze + (((long)(n * 64 + oc) * 64) + oh0 + row) * 64 + 32 * half + 4 * j) = v;
    }
  }
}

// ------------------------------ vq (MFMA) ----------------------------------
// block: (n,h) -> 64 rows (= all c). wave wv: m-tile rows c=16wv..+15 vs 512 codes.
__global__ __launch_bounds__(256) void k_vq(const short* __restrict__ zeb,
                                            const short* __restrict__ cbb,
                                            const float* __restrict__ cnm,
                                            const float* __restrict__ cb,
                                            float* __restrict__ zq,
                                            short* __restrict__ zqT) {
  const int tid = threadIdx.x;
  const int wv = tid >> 6, l = tid & 63;
  const int e = l & 15, kg = l >> 4;
  const int b = blockIdx.x;
  const int n = b >> 6, h = b & 63;

  const short* zebase = zeb + (((long)(n * 64 + 16 * wv + e) * 64) + h) * 64;
  short8 aF0 = *(const short8*)(zebase + 8 * kg);
  short8 aF1 = *(const short8*)(zebase + 32 + 8 * kg);

  float bestD[4];
  int bestI[4];
#pragma unroll
  for (int rr = 0; rr < 4; ++rr) { bestD[rr] = 3.4e38f; bestI[rr] = 0; }

  for (int ch = 0; ch < 8; ++ch) {
    f32x4 acc[4];
#pragma unroll
    for (int nt = 0; nt < 4; ++nt) {
      acc[nt] = (f32x4){0.f, 0.f, 0.f, 0.f};
      const short* cbase = cbb + (ch * 64 + nt * 16 + e) * 64;
      short8 b0 = *(const short8*)(cbase + 8 * kg);
      short8 b1 = *(const short8*)(cbase + 32 + 8 * kg);
      acc[nt] = MFMA16(aF0, b0, acc[nt]);
      acc[nt] = MFMA16(aF1, b1, acc[nt]);
    }
#pragma unroll
    for (int nt = 0; nt < 4; ++nt) {
      int code = ch * 64 + nt * 16 + e;
      float cn = cnm[code];
#pragma unroll
      for (int rr = 0; rr < 4; ++rr) {
        float d = cn - 2.f * acc[nt][rr];
        if (d < bestD[rr]) { bestD[rr] = d; bestI[rr] = code; }
      }
    }
  }
  // reduce across the 16 lanes of each row group (xor masks stay within e bits)
#pragma unroll
  for (int m = 1; m <= 8; m <<= 1) {
#pragma unroll
    for (int rr = 0; rr < 4; ++rr) {
      float od = __shfl_xor(bestD[rr], m);
      int oi = __shfl_xor(bestI[rr], m);
      if (od < bestD[rr] || (od == bestD[rr] && oi < bestI[rr])) {
        bestD[rr] = od; bestI[rr] = oi;
      }
    }
  }
  // write: row c = 16wv + 4kg + rr; lane e writes elems 4e..4e+3 (fp32 exact)
#pragma unroll
  for (int rr = 0; rr < 4; ++rr) {
    int c = 16 * wv + 4 * kg + rr;
    int idx = bestI[rr];
    float4 v = *(const float4*)(cb + idx * 64 + 4 * e);
    *(float4*)(zq + (((long)(n * 64 + c) * 64) + h) * 64 + 4 * e) = v;
    short* qt = zqT + (((long)(n * 64 + h) * 64) + 4 * e) * 64 + c;
    qt[0] = f2bf(v.x);
    qt[64] = f2bf(v.y);
    qt[128] = f2bf(v.z);
    qt[192] = f2bf(v.w);
  }
}

// ------------------------------ deconv1 (MFMA, parity) ---------------------
// block: (n, i) -> output rows oh=2i,2i+1. wave = parity p (ph,pw).
// K per parity = 4 taps x 64 c. slab [3][66][72c] bf16 from zqT.
__global__ __launch_bounds__(256) void k_deconv1(const short* __restrict__ zqT,
                                                 const short* __restrict__ AD1,
                                                 const float* __restrict__ db1,
                                                 short* __restrict__ hT) {
  __shared__ char smemD[34816];   // slab 28512 B / sOut [4][64][68] alias
  __shared__ float sBias[64];
  short* slab = (short*)smemD;
  short* sOut = (short*)smemD;

  const int tid = threadIdx.x;
  if (tid < 64) sBias[tid] = db1[tid];
  const int b = blockIdx.x;
  const int n = b >> 6, i0 = b & 63;
  const int w = tid >> 6, l = tid & 63;
  const int ph = w >> 1, pw = w & 1;
  const int e = l & 15, kg = l >> 4;

  // stage slab: ih = i0-1..i0+1, iw = -1..64 -> zeros OOB
  for (int i = tid; i < 1584; i += 256) {   // 3*66*8 lines
    int r = i / 528;
    int rem = i - r * 528;
    int iwL = rem >> 3, li = rem & 7;
    int ih = i0 - 1 + r, iw = iwL - 1;
    short8 v = {0, 0, 0, 0, 0, 0, 0, 0};
    if ((unsigned)ih < 64u && (unsigned)iw < 64u)
      v = *(const short8*)(zqT + (((long)(n * 64 + ih) * 64) + iw) * 64 + 8 * li);
    *(short8*)&slab[(r * 66 + iwL) * 72 + 8 * li] = v;
  }
  __syncthreads();

  f32x4 acc[4][4];
#pragma unroll
  for (int m = 0; m < 4; ++m)
#pragma unroll
    for (int nt = 0; nt < 4; ++nt) acc[m][nt] = (f32x4){0.f, 0.f, 0.f, 0.f};

  for (int ab = 0; ab < 4; ++ab) {
    const int rL = 1 + ph - (ab >> 1);
    const int coff = pw - (ab & 1) + 1;   // iwL = owIdx + coff
#pragma unroll
    for (int ks = 0; ks < 2; ++ks) {
      short8 aF[4], bF[4];
#pragma unroll
      for (int m = 0; m < 4; ++m)
        aF[m] = *(const short8*)(AD1 + (((w * 4 + ab) * 64 + 16 * m + e) * 64) + 32 * ks + 8 * kg);
#pragma unroll
      for (int nt = 0; nt < 4; ++nt) {
        int iwL = nt * 16 + e + coff;
        bF[nt] = *(const short8*)&slab[(rL * 66 + iwL) * 72 + 32 * ks + 8 * kg];
      }
#pragma unroll
      for (int m = 0; m < 4; ++m)
#pragma unroll
        for (int nt = 0; nt < 4; ++nt)
          acc[m][nt] = MFMA16(aF[m], bF[nt], acc[m][nt]);
    }
  }

  // epilogue: bias+relu, pack 4 oc -> sOut[w][owIdx][oc] -> hT[n][oh][ow][oc]
  __syncthreads();
#pragma unroll
  for (int m = 0; m < 4; ++m)
#pragma unroll
    for (int nt = 0; nt < 4; ++nt) {
      int owIdx = nt * 16 + e;
      int oc0 = 16 * m + 4 * kg;
      short4v o;
#pragma unroll
      for (int rr = 0; rr < 4; ++rr) {
        float v = acc[m][nt][rr] + sBias[oc0 + rr];
        o[rr] = f2bf(v > 0.f ? v : 0.f);
      }
      *(short4v*)&sOut[((w * 64 + owIdx) * 68) + oc0] = o;
    }
  __syncthreads();
  {
    const int oh = 2 * i0 + ph;
    const int ow = 2 * l + pw;
    short* dst = hT + (((long)(n * 128 + oh) * 128) + ow) * 64;
#pragma unroll
    for (int j = 0; j < 16; ++j) {
      short4v v = *(const short4v*)&sOut[((w * 64 + l) * 68) + 4 * j];
      *(short4v*)(dst + 4 * j) = v;
    }
  }
}

// ------------------------------ deconv2 (fp32, parity waves) ---------------
// block: 32x32 output tile. wave = parity class; lane has 4 positions.
__global__ __launch_bounds__(256) void k_deconv2(const short* __restrict__ hT,
                                                 const float* __restrict__ dw2,
                                                 const float* __restrict__ db2,
                                                 float* __restrict__ xr) {
  __shared__ float sW[3072];
  __shared__ float sB2[3];
  __shared__ float sIn[18 * 18 * 9];
  const int tid = threadIdx.x;
  for (int i = tid; i < 3072; i += 256) sW[i] = dw2[i];
  if (tid < 3) sB2[tid] = db2[tid];

  const int b = blockIdx.x;
  const int n = b >> 6, tile = b & 63;
  const int oh0 = (tile >> 3) * 32, ow0 = (tile & 7) * 32;
  const int w = tid >> 6, l = tid & 63;
  const int ph = w >> 1, pw = w & 1;
  const int ihBase = (oh0 >> 1) - 1, iwBase = (ow0 >> 1) - 1;

  int py[4], px[4];
#pragma unroll
  for (int s = 0; s < 4; ++s) {
    int pos = 64 * s + l;
    py[s] = pos >> 4;
    px[s] = pos & 15;
  }
  float acc[4][3];
#pragma unroll
  for (int s = 0; s < 4; ++s) acc[s][0] = acc[s][1] = acc[s][2] = 0.f;

  for (int c0 = 0; c0 < 64; c0 += 8) {
    __syncthreads();
    for (int i = tid; i < 2592; i += 256) {   // 18*18*8
      int r = i / 144;
      int rem = i - r * 144;
      int col = rem >> 3, cc = rem & 7;
      int ih = ihBase + r, iw = iwBase + col;
      float v = 0.f;
      if ((unsigned)ih < 128u && (unsigned)iw < 128u)
        v = bf2f(hT[(((long)(n * 128 + ih) * 128) + iw) * 64 + c0 + cc]);
      sIn[(r * 18 + col) * 9 + cc] = v;
    }
    __syncthreads();

#pragma unroll
    for (int ab = 0; ab < 4; ++ab) {
      const int a = ab >> 1, bb2 = ab & 1;
      const int t = (1 - ph + 2 * a) * 4 + (1 - pw + 2 * bb2);
      const int dr = ph - a + 1, dc = pw - bb2 + 1;
      for (int cc = 0; cc < 8; ++cc) {
        float w0 = sW[((c0 + cc) * 3 + 0) * 16 + t];
        float w1 = sW[((c0 + cc) * 3 + 1) * 16 + t];
        float w2v = sW[((c0 + cc) * 3 + 2) * 16 + t];
#pragma unroll
        for (int s = 0; s < 4; ++s) {
          float v = sIn[((py[s] + dr) * 18 + px[s] + dc) * 9 + cc];
          acc[s][0] += v * w0;
          acc[s][1] += v * w1;
          acc[s][2] += v * w2v;
        }
      }
    }
  }

#pragma unroll
  for (int s = 0; s < 4; ++s) {
    int oh = oh0 + 2 * py[s] + ph;
    int ow = ow0 + 2 * px[s] + pw;
#pragma unroll
    for (int o = 0; o < 3; ++o) {
      float v = 1.f / (1.f + expf(-(acc[s][o] + sB2[o])));
      xr[(((long)(n * 3 + o) * 256) + oh) * 256 + ow] = v;
    }
  }
}

// ------------------------------ launch -------------------------------------
extern "C" void kernel_launch(void* const* d_in, const int* in_sizes, int n_in,
                              void* d_out, int out_size, void* d_ws, size_t ws_size,
                              hipStream_t stream) {
  (void)in_sizes; (void)n_in; (void)out_size; (void)ws_size;

  const float* x   = (const float*)d_in[0];
  const float* w1  = (const float*)d_in[1];
  const float* b1  = (const float*)d_in[2];
  const float* w2  = (const float*)d_in[3];
  const float* b2  = (const float*)d_in[4];
  const float* cb  = (const float*)d_in[5];
  const float* dw1 = (const float*)d_in[6];
  const float* db1 = (const float*)d_in[7];
  const float* dw2 = (const float*)d_in[8];
  const float* db2 = (const float*)d_in[9];

  char* wsb = (char*)d_ws;
  short* z1T = (short*)wsb;                        // 67,108,864 B (also hT)
  short* zeb = (short*)(wsb + 67108864);           // 16,777,216 B
  short* zqT = (short*)(wsb + 83886080);           // 16,777,216 B
  short* A2  = (short*)(wsb + 100663296);          //    131,072 B
  short* AD1 = (short*)(wsb + 100794368);          //    131,072 B
  short* cbb = (short*)(wsb + 100925440);          //     65,536 B
  float* cnm = (float*)(wsb + 100990976);          //      2,048 B
  short* hT  = z1T;                                // alias (z1T dead after conv2)

  float* xr = (float*)d_out;                       // 6,291,456 f32
  float* zq = (float*)d_out + 6291456;             // 8,388,608 f32

  k_prep<<<256, 256, 0, stream>>>(w2, dw1, cb, A2, AD1, cbb, cnm);
  k_conv1<<<2048, 256, 0, stream>>>(x, w1, b1, z1T);
  k_conv2<<<1024, 256, 0, stream>>>(z1T, A2, b2, zeb);
  k_vq<<<2048, 256, 0, stream>>>(zeb, cbb, cnm, cb, zq, zqT);
  k_deconv1<<<2048, 256, 0, stream>>>(zqT, AD1, db1, hT);
  k_deconv2<<<2048, 256, 0, stream>>>(hT, dw2, db2, xr);
}

// Round 3
// 503.501 us; speedup vs baseline: 4.1950x; 1.0553x over previous
//
#include <hip/hip_runtime.h>
#include <math.h>

// ---------------------------------------------------------------------------
// VQ-VAE forward, bf16-MFMA version (R3: deconv2 -> MFMA).
//   conv1 (fp32 VALU) -> z1T [n][128][128][64c] bf16
//   conv2 (MFMA)      -> ze  [n][64c][64][64]   bf16 (NCHW)
//   vq    (MFMA)      -> zq  fp32 d_out (exact cb rows) + zqT [n][64][64][64c] bf16
//   deconv1 (MFMA)    -> hT  [n][128][128][64c] bf16 (aliases z1T)
//   deconv2 (MFMA)    -> xr  fp32 d_out (M=16 padded, 3 real oc)
// ---------------------------------------------------------------------------

typedef __attribute__((ext_vector_type(8))) short short8;
typedef __attribute__((ext_vector_type(4))) short short4v;
typedef __attribute__((ext_vector_type(4))) float f32x4;

#define MFMA16(a, b, c) __builtin_amdgcn_mfma_f32_16x16x32_bf16((a), (b), (c), 0, 0, 0)

__device__ __forceinline__ short f2bf(float f) {
  union { float f; unsigned u; } x; x.f = f;
  unsigned r = (x.u + 0x7FFFu + ((x.u >> 16) & 1u)) >> 16;
  return (short)r;
}
__device__ __forceinline__ float bf2f(short s) {
  union { unsigned u; float f; } x;
  x.u = ((unsigned)(unsigned short)s) << 16;
  return x.f;
}

// ------------------------------ prep ---------------------------------------
// A2 [t16][oc64][c64]       = w2[oc][c][t]
// AD1[p4][ab4][oc64][c64]   = dw1[c][oc][kh][kw]
// AD2[p4][ab4][oc16][c64]   = dw2[c][oc][kh][kw] (oc<3, else 0)
// cbb[512][64] bf16, cnm[512] = ||cb_k||^2 fp32
__global__ __launch_bounds__(256) void k_prep(const float* __restrict__ w2,
                                              const float* __restrict__ dw1,
                                              const float* __restrict__ dw2,
                                              const float* __restrict__ cb,
                                              short* __restrict__ A2,
                                              short* __restrict__ AD1,
                                              short* __restrict__ AD2,
                                              short* __restrict__ cbb,
                                              float* __restrict__ cnm) {
  int i = blockIdx.x * 256 + threadIdx.x;  // 0..65535
  {
    int t = i >> 12, oc = (i >> 6) & 63, c = i & 63;
    A2[i] = f2bf(w2[(oc * 64 + c) * 16 + t]);
  }
  {
    int p = i >> 14, ab = (i >> 12) & 3, oc = (i >> 6) & 63, c = i & 63;
    int kh = 1 - (p >> 1) + 2 * (ab >> 1);
    int kw = 1 - (p & 1) + 2 * (ab & 1);
    AD1[i] = f2bf(dw1[(c * 64 + oc) * 16 + kh * 4 + kw]);
  }
  if (i < 16384) {
    int p = i >> 12, ab = (i >> 10) & 3, oc = (i >> 6) & 15, c = i & 63;
    int kh = 1 - (p >> 1) + 2 * (ab >> 1);
    int kw = 1 - (p & 1) + 2 * (ab & 1);
    short v = 0;
    if (oc < 3) v = f2bf(dw2[(c * 3 + oc) * 16 + kh * 4 + kw]);
    AD2[i] = v;
  }
  if (i < 32768) cbb[i] = f2bf(cb[i]);
  if (i < 512) {
    float s = 0.f;
    for (int d = 0; d < 64; ++d) { float v = cb[i * 64 + d]; s += v * v; }
    cnm[i] = s;
  }
}

// ------------------------------ conv1 --------------------------------------
__global__ __launch_bounds__(256) void k_conv1(const float* __restrict__ x,
                                               const float* __restrict__ w1,
                                               const float* __restrict__ b1,
                                               short* __restrict__ z1T) {
  __shared__ float sW[3 * 16 * 64];
  __shared__ float sB[64];
  __shared__ float sIn[3 * 34 * 34];
  __shared__ short sOutC[256 * 72];
  const int tid = threadIdx.x;

  for (int i = tid; i < 3072; i += 256) {
    int oc = i & 63, t = (i >> 6) & 15, c = i >> 10;
    sW[i] = w1[(oc * 3 + c) * 16 + t];
  }
  if (tid < 64) sB[tid] = b1[tid];

  const int b = blockIdx.x;
  const int n = b >> 6;
  const int tile = b & 63;
  const int tr = tile >> 3, tc = tile & 7;
  const int oh0 = tr * 16, ow0 = tc * 16;
  const int ih_base = oh0 * 2 - 1, iw_base = ow0 * 2 - 1;

  for (int i = tid; i < 3468; i += 256) {
    int c = i / 1156;
    int rem = i - c * 1156;
    int r = rem / 34;
    int col = rem - r * 34;
    int ih = ih_base + r, iw = iw_base + col;
    float v = 0.f;
    if ((unsigned)ih < 256u && (unsigned)iw < 256u)
      v = x[((n * 3 + c) * 256 + ih) * 256 + iw];
    sIn[i] = v;
  }
  __syncthreads();

  const int ty = tid >> 4, tx = tid & 15;
  float acc[64];
#pragma unroll
  for (int j = 0; j < 64; ++j) acc[j] = sB[j];

  for (int c = 0; c < 3; ++c) {
    for (int t = 0; t < 16; ++t) {
      int kh = t >> 2, kw = t & 3;
      float v = sIn[c * 1156 + (2 * ty + kh) * 34 + (2 * tx + kw)];
      const float4* wp = (const float4*)&sW[(c * 16 + t) * 64];
#pragma unroll
      for (int j = 0; j < 16; ++j) {
        float4 w4 = wp[j];
        acc[4 * j + 0] += v * w4.x;
        acc[4 * j + 1] += v * w4.y;
        acc[4 * j + 2] += v * w4.z;
        acc[4 * j + 3] += v * w4.w;
      }
    }
  }

  // relu + bf16 -> LDS transpose -> coalesced z1T[n][oh][ow][c]
  const int sp = ty * 16 + tx;
#pragma unroll
  for (int kk = 0; kk < 8; ++kk) {
    short8 v;
#pragma unroll
    for (int t2 = 0; t2 < 8; ++t2) {
      float r = acc[8 * kk + t2];
      v[t2] = f2bf(r > 0.f ? r : 0.f);
    }
    *(short8*)&sOutC[sp * 72 + 8 * kk] = v;
  }
  __syncthreads();
  const int r = tid >> 4, jj = tid & 15;
#pragma unroll
  for (int it = 0; it < 8; ++it) {
    int chunk = jj + 16 * it;
    int owL = chunk >> 3, c8 = chunk & 7;
    short8 v = *(const short8*)&sOutC[(r * 16 + owL) * 72 + 8 * c8];
    *(short8*)(z1T + (((long)(n * 128 + oh0 + r) * 128) + ow0 + owL) * 64 + 8 * c8) = v;
  }
}

// ------------------------------ conv2 (MFMA) -------------------------------
__global__ __launch_bounds__(256) void k_conv2(const short* __restrict__ z1T,
                                               const short* __restrict__ A2,
                                               const float* __restrict__ b2,
                                               short* __restrict__ ze) {
  __shared__ char smemC[62400];
  __shared__ float sB2c[64];
  short* slab = (short*)smemC;
  short* sOut = (short*)smemC;

  const int tid = threadIdx.x;
  if (tid < 64) sB2c[tid] = b2[tid];
  const int b = blockIdx.x;
  const int n = b >> 5;
  const int oh0 = (b & 31) * 2;
  const int w = tid >> 6, l = tid & 63;
  const int row = w >> 1, mh = w & 1;
  const int e = l & 15, kg = l >> 4;
  const int ih0 = 2 * oh0 - 1;

  f32x4 acc[2][4];
#pragma unroll
  for (int mi = 0; mi < 2; ++mi)
#pragma unroll
    for (int nt = 0; nt < 4; ++nt) acc[mi][nt] = (f32x4){0.f, 0.f, 0.f, 0.f};

  for (int p = 0; p < 2; ++p) {
    const int c0 = 32 * p;
    __syncthreads();
    for (int i = tid; i < 3120; i += 256) {
      int r = i / 520;
      int rem = i - r * 520;
      int iwL = rem >> 2, li = rem & 3;
      int ih = ih0 + r, iw = iwL - 1;
      short8 v = {0, 0, 0, 0, 0, 0, 0, 0};
      if ((unsigned)ih < 128u && (unsigned)iw < 128u)
        v = *(const short8*)(z1T + (((long)(n * 128 + ih) * 128) + iw) * 64 + c0 + 8 * li);
      *(short8*)&slab[8 * ((r * 130 + iwL) * 5 + li)] = v;
    }
    __syncthreads();

    for (int t = 0; t < 16; ++t) {
      const int kh = t >> 2, kw = t & 3;
      const int rL = 2 * row + kh;
      short8 aF[2], bF[4];
#pragma unroll
      for (int mi = 0; mi < 2; ++mi)
        aF[mi] = *(const short8*)(A2 + ((t * 64 + 32 * mh + 16 * mi + e) * 64) + c0 + 8 * kg);
#pragma unroll
      for (int nt = 0; nt < 4; ++nt) {
        int iwL = 2 * (nt * 16 + e) + kw;
        bF[nt] = *(const short8*)&slab[8 * ((rL * 130 + iwL) * 5 + kg)];
      }
#pragma unroll
      for (int mi = 0; mi < 2; ++mi)
#pragma unroll
        for (int nt = 0; nt < 4; ++nt)
          acc[mi][nt] = MFMA16(aF[mi], bF[nt], acc[mi][nt]);
    }
  }

  __syncthreads();
#pragma unroll
  for (int mi = 0; mi < 2; ++mi)
#pragma unroll
    for (int nt = 0; nt < 4; ++nt)
#pragma unroll
      for (int rr = 0; rr < 4; ++rr) {
        int oc = 32 * mh + 16 * mi + 4 * kg + rr;
        float v = acc[mi][nt][rr] + sB2c[oc];
        sOut[(row * 64 + oc) * 68 + nt * 16 + e] = f2bf(v > 0.f ? v : 0.f);
      }
  __syncthreads();
  {
    int oc = 32 * mh + (l >> 1);
    int half = l & 1;
#pragma unroll
    for (int j = 0; j < 8; ++j) {
      short4v v = *(const short4v*)&sOut[(row * 64 + oc) * 68 + 32 * half + 4 * j];
      *(short4v*)(ze + (((long)(n * 64 + oc) * 64) + oh0 + row) * 64 + 32 * half + 4 * j) = v;
    }
  }
}

// ------------------------------ vq (MFMA) ----------------------------------
__global__ __launch_bounds__(256) void k_vq(const short* __restrict__ zeb,
                                            const short* __restrict__ cbb,
                                            const float* __restrict__ cnm,
                                            const float* __restrict__ cb,
                                            float* __restrict__ zq,
                                            short* __restrict__ zqT) {
  const int tid = threadIdx.x;
  const int wv = tid >> 6, l = tid & 63;
  const int e = l & 15, kg = l >> 4;
  const int b = blockIdx.x;
  const int n = b >> 6, h = b & 63;

  const short* zebase = zeb + (((long)(n * 64 + 16 * wv + e) * 64) + h) * 64;
  short8 aF0 = *(const short8*)(zebase + 8 * kg);
  short8 aF1 = *(const short8*)(zebase + 32 + 8 * kg);

  float bestD[4];
  int bestI[4];
#pragma unroll
  for (int rr = 0; rr < 4; ++rr) { bestD[rr] = 3.4e38f; bestI[rr] = 0; }

  for (int ch = 0; ch < 8; ++ch) {
    f32x4 acc[4];
#pragma unroll
    for (int nt = 0; nt < 4; ++nt) {
      acc[nt] = (f32x4){0.f, 0.f, 0.f, 0.f};
      const short* cbase = cbb + (ch * 64 + nt * 16 + e) * 64;
      short8 b0 = *(const short8*)(cbase + 8 * kg);
      short8 b1 = *(const short8*)(cbase + 32 + 8 * kg);
      acc[nt] = MFMA16(aF0, b0, acc[nt]);
      acc[nt] = MFMA16(aF1, b1, acc[nt]);
    }
#pragma unroll
    for (int nt = 0; nt < 4; ++nt) {
      int code = ch * 64 + nt * 16 + e;
      float cn = cnm[code];
#pragma unroll
      for (int rr = 0; rr < 4; ++rr) {
        float d = cn - 2.f * acc[nt][rr];
        if (d < bestD[rr]) { bestD[rr] = d; bestI[rr] = code; }
      }
    }
  }
#pragma unroll
  for (int m = 1; m <= 8; m <<= 1) {
#pragma unroll
    for (int rr = 0; rr < 4; ++rr) {
      float od = __shfl_xor(bestD[rr], m);
      int oi = __shfl_xor(bestI[rr], m);
      if (od < bestD[rr] || (od == bestD[rr] && oi < bestI[rr])) {
        bestD[rr] = od; bestI[rr] = oi;
      }
    }
  }
#pragma unroll
  for (int rr = 0; rr < 4; ++rr) {
    int c = 16 * wv + 4 * kg + rr;
    int idx = bestI[rr];
    float4 v = *(const float4*)(cb + idx * 64 + 4 * e);
    *(float4*)(zq + (((long)(n * 64 + c) * 64) + h) * 64 + 4 * e) = v;
    short* qt = zqT + (((long)(n * 64 + h) * 64) + 4 * e) * 64 + c;
    qt[0] = f2bf(v.x);
    qt[64] = f2bf(v.y);
    qt[128] = f2bf(v.z);
    qt[192] = f2bf(v.w);
  }
}

// ------------------------------ deconv1 (MFMA, parity) ---------------------
__global__ __launch_bounds__(256) void k_deconv1(const short* __restrict__ zqT,
                                                 const short* __restrict__ AD1,
                                                 const float* __restrict__ db1,
                                                 short* __restrict__ hT) {
  __shared__ char smemD[34816];
  __shared__ float sBias[64];
  short* slab = (short*)smemD;
  short* sOut = (short*)smemD;

  const int tid = threadIdx.x;
  if (tid < 64) sBias[tid] = db1[tid];
  const int b = blockIdx.x;
  const int n = b >> 6, i0 = b & 63;
  const int w = tid >> 6, l = tid & 63;
  const int ph = w >> 1, pw = w & 1;
  const int e = l & 15, kg = l >> 4;

  for (int i = tid; i < 1584; i += 256) {
    int r = i / 528;
    int rem = i - r * 528;
    int iwL = rem >> 3, li = rem & 7;
    int ih = i0 - 1 + r, iw = iwL - 1;
    short8 v = {0, 0, 0, 0, 0, 0, 0, 0};
    if ((unsigned)ih < 64u && (unsigned)iw < 64u)
      v = *(const short8*)(zqT + (((long)(n * 64 + ih) * 64) + iw) * 64 + 8 * li);
    *(short8*)&slab[(r * 66 + iwL) * 72 + 8 * li] = v;
  }
  __syncthreads();

  f32x4 acc[4][4];
#pragma unroll
  for (int m = 0; m < 4; ++m)
#pragma unroll
    for (int nt = 0; nt < 4; ++nt) acc[m][nt] = (f32x4){0.f, 0.f, 0.f, 0.f};

  for (int ab = 0; ab < 4; ++ab) {
    const int rL = 1 + ph - (ab >> 1);
    const int coff = pw - (ab & 1) + 1;
#pragma unroll
    for (int ks = 0; ks < 2; ++ks) {
      short8 aF[4], bF[4];
#pragma unroll
      for (int m = 0; m < 4; ++m)
        aF[m] = *(const short8*)(AD1 + (((w * 4 + ab) * 64 + 16 * m + e) * 64) + 32 * ks + 8 * kg);
#pragma unroll
      for (int nt = 0; nt < 4; ++nt) {
        int iwL = nt * 16 + e + coff;
        bF[nt] = *(const short8*)&slab[(rL * 66 + iwL) * 72 + 32 * ks + 8 * kg];
      }
#pragma unroll
      for (int m = 0; m < 4; ++m)
#pragma unroll
        for (int nt = 0; nt < 4; ++nt)
          acc[m][nt] = MFMA16(aF[m], bF[nt], acc[m][nt]);
    }
  }

  __syncthreads();
#pragma unroll
  for (int m = 0; m < 4; ++m)
#pragma unroll
    for (int nt = 0; nt < 4; ++nt) {
      int owIdx = nt * 16 + e;
      int oc0 = 16 * m + 4 * kg;
      short4v o;
#pragma unroll
      for (int rr = 0; rr < 4; ++rr) {
        float v = acc[m][nt][rr] + sBias[oc0 + rr];
        o[rr] = f2bf(v > 0.f ? v : 0.f);
      }
      *(short4v*)&sOut[((w * 64 + owIdx) * 68) + oc0] = o;
    }
  __syncthreads();
  {
    const int oh = 2 * i0 + ph;
    const int ow = 2 * l + pw;
    short* dst = hT + (((long)(n * 128 + oh) * 128) + ow) * 64;
#pragma unroll
    for (int j = 0; j < 16; ++j) {
      short4v v = *(const short4v*)&sOut[((w * 64 + l) * 68) + 4 * j];
      *(short4v*)(dst + 4 * j) = v;
    }
  }
}

// ------------------------------ deconv2 (MFMA, parity) ---------------------
// block: (n, q, wh). output rows oh = 8q..8q+7, cols ow = 128*wh..+127.
// wave = parity (ph,pw); per wave: 4 oh rows x 64 ow positions = 16 n-tiles.
// M = 16 (3 real oc), K = 256 = 4 taps(ab) x 64 c.
__global__ __launch_bounds__(256) void k_deconv2(const short* __restrict__ hT,
                                                 const short* __restrict__ AD2,
                                                 const float* __restrict__ db2,
                                                 float* __restrict__ xr) {
  __shared__ char smemE[53856];        // sIn [6][66][68] bf16; sOut alias 12288 B
  __shared__ float sB2[3];
  short* sIn = (short*)smemE;
  float* sOut = (float*)smemE;         // [3 oc][8 ohl][128 owl]

  const int tid = threadIdx.x;
  if (tid < 3) sB2[tid] = db2[tid];
  const int b = blockIdx.x;
  const int n = b >> 6;
  const int rem0 = b & 63;
  const int q = rem0 >> 1, wh = rem0 & 1;
  const int w = tid >> 6, l = tid & 63;
  const int ph = w >> 1, pw = w & 1;
  const int e = l & 15, kg = l >> 4;

  // stage slab: ih = 4q-1..4q+4, iw = 64wh-1..64wh+64; 3168 short8 lines
  for (int i = tid; i < 3168; i += 256) {
    int r = i / 528;
    int rr2 = i - r * 528;
    int iwL = rr2 >> 3, li = rr2 & 7;
    int ih = 4 * q - 1 + r, iw = 64 * wh - 1 + iwL;
    short8 v = {0, 0, 0, 0, 0, 0, 0, 0};
    if ((unsigned)ih < 128u && (unsigned)iw < 128u)
      v = *(const short8*)(hT + (((long)(n * 128 + ih) * 128) + iw) * 64 + 8 * li);
    *(short8*)&sIn[(r * 66 + iwL) * 68 + 8 * li] = v;
  }

  // preload A fragments: 8 K-steps (ab, ch)
  short8 aF[8];
#pragma unroll
  for (int ab = 0; ab < 4; ++ab)
#pragma unroll
    for (int chh = 0; chh < 2; ++chh)
      aF[ab * 2 + chh] = *(const short8*)(AD2 + (((w * 4 + ab) * 16 + e) * 64) + 32 * chh + 8 * kg);

  __syncthreads();

  f32x4 acc[4][4];   // [j row][nt]
#pragma unroll
  for (int j = 0; j < 4; ++j)
#pragma unroll
    for (int nt = 0; nt < 4; ++nt) acc[j][nt] = (f32x4){0.f, 0.f, 0.f, 0.f};

  const int colBase = e + pw + 1;     // iwL = nt*16 + colBase - b
  const int rowBase = 1 + ph;         // rL  = rowBase + j - a

#pragma unroll
  for (int ab = 0; ab < 4; ++ab) {
    const int a = ab >> 1, bb = ab & 1;
#pragma unroll
    for (int chh = 0; chh < 2; ++chh) {
      short8 af = aF[ab * 2 + chh];
#pragma unroll
      for (int j = 0; j < 4; ++j) {
        const int rL = rowBase + j - a;
#pragma unroll
        for (int nt = 0; nt < 4; ++nt) {
          const int iwL = nt * 16 + colBase - bb;
          short8 bf = *(const short8*)&sIn[(rL * 66 + iwL) * 68 + 32 * chh + 8 * kg];
          acc[j][nt] = MFMA16(af, bf, acc[j][nt]);
        }
      }
    }
  }

  __syncthreads();   // all waves done reading sIn before sOut overwrite
  if (kg == 0) {
#pragma unroll
    for (int j = 0; j < 4; ++j)
#pragma unroll
      for (int nt = 0; nt < 4; ++nt) {
        int ohl = 2 * j + ph;
        int owl = 2 * (nt * 16 + e) + pw;
#pragma unroll
        for (int rr = 0; rr < 3; ++rr) {
          float v = 1.f / (1.f + expf(-(acc[j][nt][rr] + sB2[rr])));
          sOut[(rr * 8 + ohl) * 128 + owl] = v;
        }
      }
  }
  __syncthreads();
  for (int i = tid; i < 768; i += 256) {
    int oc = i >> 8, r2 = i & 255;
    int ohl = r2 >> 5, c4 = r2 & 31;
    float4 v = ((const float4*)sOut)[i];
    *(float4*)(xr + (((long)(n * 3 + oc) * 256) + 8 * q + ohl) * 256 + 128 * wh + 4 * c4) = v;
  }
}

// ------------------------------ launch -------------------------------------
extern "C" void kernel_launch(void* const* d_in, const int* in_sizes, int n_in,
                              void* d_out, int out_size, void* d_ws, size_t ws_size,
                              hipStream_t stream) {
  (void)in_sizes; (void)n_in; (void)out_size; (void)ws_size;

  const float* x   = (const float*)d_in[0];
  const float* w1  = (const float*)d_in[1];
  const float* b1  = (const float*)d_in[2];
  const float* w2  = (const float*)d_in[3];
  const float* b2  = (const float*)d_in[4];
  const float* cb  = (const float*)d_in[5];
  const float* dw1 = (const float*)d_in[6];
  const float* db1 = (const float*)d_in[7];
  const float* dw2 = (const float*)d_in[8];
  const float* db2 = (const float*)d_in[9];

  char* wsb = (char*)d_ws;
  short* z1T = (short*)wsb;                        // 67,108,864 B (also hT)
  short* zeb = (short*)(wsb + 67108864);           // 16,777,216 B
  short* zqT = (short*)(wsb + 83886080);           // 16,777,216 B
  short* A2  = (short*)(wsb + 100663296);          //    131,072 B
  short* AD1 = (short*)(wsb + 100794368);          //    131,072 B
  short* cbb = (short*)(wsb + 100925440);          //     65,536 B
  float* cnm = (float*)(wsb + 100990976);          //      2,048 B
  short* AD2 = (short*)(wsb + 100993024);          //     32,768 B
  short* hT  = z1T;                                // alias (z1T dead after conv2)

  float* xr = (float*)d_out;                       // 6,291,456 f32
  float* zq = (float*)d_out + 6291456;             // 8,388,608 f32

  k_prep<<<256, 256, 0, stream>>>(w2, dw1, dw2, cb, A2, AD1, AD2, cbb, cnm);
  k_conv1<<<2048, 256, 0, stream>>>(x, w1, b1, z1T);
  k_conv2<<<1024, 256, 0, stream>>>(z1T, A2, b2, zeb);
  k_vq<<<2048, 256, 0, stream>>>(zeb, cbb, cnm, cb, zq, zqT);
  k_deconv1<<<2048, 256, 0, stream>>>(zqT, AD1, db1, hT);
  k_deconv2<<<2048, 256, 0, stream>>>(hT, AD2, db2, xr);
}

// Round 4
// 458.241 us; speedup vs baseline: 4.6093x; 1.0988x over previous
//
#include <hip/hip_runtime.h>
#include <math.h>

// ---------------------------------------------------------------------------
// VQ-VAE forward, bf16-MFMA version (R4: batched staging + deconv2 occupancy).
//   conv1 (fp32 VALU) -> z1T [n][128][128][64c] bf16
//   conv2 (MFMA)      -> ze  [n][64c][64][64]   bf16 (NCHW)
//   vq    (MFMA)      -> zq  fp32 d_out (exact cb rows) + zqT [n][64][64][64c] bf16
//   deconv1 (MFMA)    -> hT  [n][128][128][64c] bf16 (aliases z1T)
//   deconv2 (MFMA)    -> xr  fp32 d_out (M=16 padded, 3 real oc; 2x32c passes)
// ---------------------------------------------------------------------------

typedef __attribute__((ext_vector_type(8))) short short8;
typedef __attribute__((ext_vector_type(4))) short short4v;
typedef __attribute__((ext_vector_type(4))) float f32x4;

#define MFMA16(a, b, c) __builtin_amdgcn_mfma_f32_16x16x32_bf16((a), (b), (c), 0, 0, 0)

__device__ __forceinline__ short f2bf(float f) {
  union { float f; unsigned u; } x; x.f = f;
  unsigned r = (x.u + 0x7FFFu + ((x.u >> 16) & 1u)) >> 16;
  return (short)r;
}
__device__ __forceinline__ float bf2f(short s) {
  union { unsigned u; float f; } x;
  x.u = ((unsigned)(unsigned short)s) << 16;
  return x.f;
}

// ------------------------------ prep ---------------------------------------
__global__ __launch_bounds__(256) void k_prep(const float* __restrict__ w2,
                                              const float* __restrict__ dw1,
                                              const float* __restrict__ dw2,
                                              const float* __restrict__ cb,
                                              short* __restrict__ A2,
                                              short* __restrict__ AD1,
                                              short* __restrict__ AD2,
                                              short* __restrict__ cbb,
                                              float* __restrict__ cnm) {
  int i = blockIdx.x * 256 + threadIdx.x;  // 0..65535
  {
    int t = i >> 12, oc = (i >> 6) & 63, c = i & 63;
    A2[i] = f2bf(w2[(oc * 64 + c) * 16 + t]);
  }
  {
    int p = i >> 14, ab = (i >> 12) & 3, oc = (i >> 6) & 63, c = i & 63;
    int kh = 1 - (p >> 1) + 2 * (ab >> 1);
    int kw = 1 - (p & 1) + 2 * (ab & 1);
    AD1[i] = f2bf(dw1[(c * 64 + oc) * 16 + kh * 4 + kw]);
  }
  if (i < 16384) {
    int p = i >> 12, ab = (i >> 10) & 3, oc = (i >> 6) & 15, c = i & 63;
    int kh = 1 - (p >> 1) + 2 * (ab >> 1);
    int kw = 1 - (p & 1) + 2 * (ab & 1);
    short v = 0;
    if (oc < 3) v = f2bf(dw2[(c * 3 + oc) * 16 + kh * 4 + kw]);
    AD2[i] = v;
  }
  if (i < 32768) cbb[i] = f2bf(cb[i]);
  if (i < 512) {
    float s = 0.f;
    for (int d = 0; d < 64; ++d) { float v = cb[i * 64 + d]; s += v * v; }
    cnm[i] = s;
  }
}

// ------------------------------ conv1 --------------------------------------
__global__ __launch_bounds__(256) void k_conv1(const float* __restrict__ x,
                                               const float* __restrict__ w1,
                                               const float* __restrict__ b1,
                                               short* __restrict__ z1T) {
  __shared__ float sW[3 * 16 * 64];
  __shared__ float sB[64];
  __shared__ float sIn[3 * 34 * 34];
  __shared__ short sOutC[256 * 72];
  const int tid = threadIdx.x;

  // batched weight stage: 3072 = 12 x 256
  {
    float tw[12];
#pragma unroll
    for (int it = 0; it < 12; ++it) {
      int i = tid + 256 * it;
      int oc = i & 63, t = (i >> 6) & 15, c = i >> 10;
      tw[it] = w1[(oc * 3 + c) * 16 + t];
    }
#pragma unroll
    for (int it = 0; it < 12; ++it) sW[tid + 256 * it] = tw[it];
  }
  if (tid < 64) sB[tid] = b1[tid];

  const int b = blockIdx.x;
  const int n = b >> 6;
  const int tile = b & 63;
  const int tr = tile >> 3, tc = tile & 7;
  const int oh0 = tr * 16, ow0 = tc * 16;
  const int ih_base = oh0 * 2 - 1, iw_base = ow0 * 2 - 1;

  // batched input stage: 3468 = 13*256 + 140
  {
    float t[14]; bool vd[14];
#pragma unroll
    for (int it = 0; it < 14; ++it) {
      int i = tid + 256 * it;
      vd[it] = i < 3468;
      int ii = vd[it] ? i : 0;
      int c = ii / 1156;
      int rem = ii - c * 1156;
      int r = rem / 34;
      int col = rem - r * 34;
      int ih = ih_base + r, iw = iw_base + col;
      float v = 0.f;
      if (vd[it] && (unsigned)ih < 256u && (unsigned)iw < 256u)
        v = x[((n * 3 + c) * 256 + ih) * 256 + iw];
      t[it] = v;
    }
#pragma unroll
    for (int it = 0; it < 14; ++it)
      if (vd[it]) sIn[tid + 256 * it] = t[it];
  }
  __syncthreads();

  const int ty = tid >> 4, tx = tid & 15;
  float acc[64];
#pragma unroll
  for (int j = 0; j < 64; ++j) acc[j] = sB[j];

  for (int c = 0; c < 3; ++c) {
    for (int t = 0; t < 16; ++t) {
      int kh = t >> 2, kw = t & 3;
      float v = sIn[c * 1156 + (2 * ty + kh) * 34 + (2 * tx + kw)];
      const float4* wp = (const float4*)&sW[(c * 16 + t) * 64];
#pragma unroll
      for (int j = 0; j < 16; ++j) {
        float4 w4 = wp[j];
        acc[4 * j + 0] += v * w4.x;
        acc[4 * j + 1] += v * w4.y;
        acc[4 * j + 2] += v * w4.z;
        acc[4 * j + 3] += v * w4.w;
      }
    }
  }

  const int sp = ty * 16 + tx;
#pragma unroll
  for (int kk = 0; kk < 8; ++kk) {
    short8 v;
#pragma unroll
    for (int t2 = 0; t2 < 8; ++t2) {
      float r = acc[8 * kk + t2];
      v[t2] = f2bf(r > 0.f ? r : 0.f);
    }
    *(short8*)&sOutC[sp * 72 + 8 * kk] = v;
  }
  __syncthreads();
  const int r = tid >> 4, jj = tid & 15;
#pragma unroll
  for (int it = 0; it < 8; ++it) {
    int chunk = jj + 16 * it;
    int owL = chunk >> 3, c8 = chunk & 7;
    short8 v = *(const short8*)&sOutC[(r * 16 + owL) * 72 + 8 * c8];
    *(short8*)(z1T + (((long)(n * 128 + oh0 + r) * 128) + ow0 + owL) * 64 + 8 * c8) = v;
  }
}

// ------------------------------ conv2 (MFMA) -------------------------------
__global__ __launch_bounds__(256) void k_conv2(const short* __restrict__ z1T,
                                               const short* __restrict__ A2,
                                               const float* __restrict__ b2,
                                               short* __restrict__ ze) {
  __shared__ char smemC[62400];
  __shared__ float sB2c[64];
  short* slab = (short*)smemC;
  short* sOut = (short*)smemC;

  const int tid = threadIdx.x;
  if (tid < 64) sB2c[tid] = b2[tid];
  const int b = blockIdx.x;
  const int n = b >> 5;
  const int oh0 = (b & 31) * 2;
  const int w = tid >> 6, l = tid & 63;
  const int row = w >> 1, mh = w & 1;
  const int e = l & 15, kg = l >> 4;
  const int ih0 = 2 * oh0 - 1;

  f32x4 acc[2][4];
#pragma unroll
  for (int mi = 0; mi < 2; ++mi)
#pragma unroll
    for (int nt = 0; nt < 4; ++nt) acc[mi][nt] = (f32x4){0.f, 0.f, 0.f, 0.f};

  for (int p = 0; p < 2; ++p) {
    const int c0 = 32 * p;
    __syncthreads();
    // batched stage, chunk A: 7 lines (all valid: max i = 1791 < 3120)
    {
      short8 ta[7]; int off[7];
#pragma unroll
      for (int it = 0; it < 7; ++it) {
        int i = tid + 256 * it;
        int r = i / 520;
        int rem = i - r * 520;
        int iwL = rem >> 2, li = rem & 3;
        int ih = ih0 + r, iw = iwL - 1;
        off[it] = 8 * ((r * 130 + iwL) * 5 + li);
        short8 v = {0, 0, 0, 0, 0, 0, 0, 0};
        if ((unsigned)ih < 128u && (unsigned)iw < 128u)
          v = *(const short8*)(z1T + (((long)(n * 128 + ih) * 128) + iw) * 64 + c0 + 8 * li);
        ta[it] = v;
      }
#pragma unroll
      for (int it = 0; it < 7; ++it) *(short8*)&slab[off[it]] = ta[it];
    }
    // chunk B: 6 lines, guarded (3120 = 12*256 + 48)
    {
      short8 tb[6]; int off[6]; bool vd[6];
#pragma unroll
      for (int it = 0; it < 6; ++it) {
        int i = tid + 256 * (7 + it);
        vd[it] = i < 3120;
        int ii = vd[it] ? i : 0;
        int r = ii / 520;
        int rem = ii - r * 520;
        int iwL = rem >> 2, li = rem & 3;
        int ih = ih0 + r, iw = iwL - 1;
        off[it] = 8 * ((r * 130 + iwL) * 5 + li);
        short8 v = {0, 0, 0, 0, 0, 0, 0, 0};
        if (vd[it] && (unsigned)ih < 128u && (unsigned)iw < 128u)
          v = *(const short8*)(z1T + (((long)(n * 128 + ih) * 128) + iw) * 64 + c0 + 8 * li);
        tb[it] = v;
      }
#pragma unroll
      for (int it = 0; it < 6; ++it)
        if (vd[it]) *(short8*)&slab[off[it]] = tb[it];
    }
    __syncthreads();

    for (int t = 0; t < 16; ++t) {
      const int kh = t >> 2, kw = t & 3;
      const int rL = 2 * row + kh;
      short8 aF[2], bF[4];
#pragma unroll
      for (int mi = 0; mi < 2; ++mi)
        aF[mi] = *(const short8*)(A2 + ((t * 64 + 32 * mh + 16 * mi + e) * 64) + c0 + 8 * kg);
#pragma unroll
      for (int nt = 0; nt < 4; ++nt) {
        int iwL = 2 * (nt * 16 + e) + kw;
        bF[nt] = *(const short8*)&slab[8 * ((rL * 130 + iwL) * 5 + kg)];
      }
#pragma unroll
      for (int mi = 0; mi < 2; ++mi)
#pragma unroll
        for (int nt = 0; nt < 4; ++nt)
          acc[mi][nt] = MFMA16(aF[mi], bF[nt], acc[mi][nt]);
    }
  }

  __syncthreads();
#pragma unroll
  for (int mi = 0; mi < 2; ++mi)
#pragma unroll
    for (int nt = 0; nt < 4; ++nt)
#pragma unroll
      for (int rr = 0; rr < 4; ++rr) {
        int oc = 32 * mh + 16 * mi + 4 * kg + rr;
        float v = acc[mi][nt][rr] + sB2c[oc];
        sOut[(row * 64 + oc) * 68 + nt * 16 + e] = f2bf(v > 0.f ? v : 0.f);
      }
  __syncthreads();
  {
    int oc = 32 * mh + (l >> 1);
    int half = l & 1;
#pragma unroll
    for (int j = 0; j < 8; ++j) {
      short4v v = *(const short4v*)&sOut[(row * 64 + oc) * 68 + 32 * half + 4 * j];
      *(short4v*)(ze + (((long)(n * 64 + oc) * 64) + oh0 + row) * 64 + 32 * half + 4 * j) = v;
    }
  }
}

// ------------------------------ vq (MFMA) ----------------------------------
__global__ __launch_bounds__(256) void k_vq(const short* __restrict__ zeb,
                                            const short* __restrict__ cbb,
                                            const float* __restrict__ cnm,
                                            const float* __restrict__ cb,
                                            float* __restrict__ zq,
                                            short* __restrict__ zqT) {
  const int tid = threadIdx.x;
  const int wv = tid >> 6, l = tid & 63;
  const int e = l & 15, kg = l >> 4;
  const int b = blockIdx.x;
  const int n = b >> 6, h = b & 63;

  const short* zebase = zeb + (((long)(n * 64 + 16 * wv + e) * 64) + h) * 64;
  short8 aF0 = *(const short8*)(zebase + 8 * kg);
  short8 aF1 = *(const short8*)(zebase + 32 + 8 * kg);

  float bestD[4];
  int bestI[4];
#pragma unroll
  for (int rr = 0; rr < 4; ++rr) { bestD[rr] = 3.4e38f; bestI[rr] = 0; }

  for (int ch = 0; ch < 8; ++ch) {
    f32x4 acc[4];
#pragma unroll
    for (int nt = 0; nt < 4; ++nt) {
      acc[nt] = (f32x4){0.f, 0.f, 0.f, 0.f};
      const short* cbase = cbb + (ch * 64 + nt * 16 + e) * 64;
      short8 b0 = *(const short8*)(cbase + 8 * kg);
      short8 b1 = *(const short8*)(cbase + 32 + 8 * kg);
      acc[nt] = MFMA16(aF0, b0, acc[nt]);
      acc[nt] = MFMA16(aF1, b1, acc[nt]);
    }
#pragma unroll
    for (int nt = 0; nt < 4; ++nt) {
      int code = ch * 64 + nt * 16 + e;
      float cn = cnm[code];
#pragma unroll
      for (int rr = 0; rr < 4; ++rr) {
        float d = cn - 2.f * acc[nt][rr];
        if (d < bestD[rr]) { bestD[rr] = d; bestI[rr] = code; }
      }
    }
  }
#pragma unroll
  for (int m = 1; m <= 8; m <<= 1) {
#pragma unroll
    for (int rr = 0; rr < 4; ++rr) {
      float od = __shfl_xor(bestD[rr], m);
      int oi = __shfl_xor(bestI[rr], m);
      if (od < bestD[rr] || (od == bestD[rr] && oi < bestI[rr])) {
        bestD[rr] = od; bestI[rr] = oi;
      }
    }
  }
#pragma unroll
  for (int rr = 0; rr < 4; ++rr) {
    int c = 16 * wv + 4 * kg + rr;
    int idx = bestI[rr];
    float4 v = *(const float4*)(cb + idx * 64 + 4 * e);
    *(float4*)(zq + (((long)(n * 64 + c) * 64) + h) * 64 + 4 * e) = v;
    short* qt = zqT + (((long)(n * 64 + h) * 64) + 4 * e) * 64 + c;
    qt[0] = f2bf(v.x);
    qt[64] = f2bf(v.y);
    qt[128] = f2bf(v.z);
    qt[192] = f2bf(v.w);
  }
}

// ------------------------------ deconv1 (MFMA, parity) ---------------------
__global__ __launch_bounds__(256) void k_deconv1(const short* __restrict__ zqT,
                                                 const short* __restrict__ AD1,
                                                 const float* __restrict__ db1,
                                                 short* __restrict__ hT) {
  __shared__ char smemD[34816];
  __shared__ float sBias[64];
  short* slab = (short*)smemD;
  short* sOut = (short*)smemD;

  const int tid = threadIdx.x;
  if (tid < 64) sBias[tid] = db1[tid];
  const int b = blockIdx.x;
  const int n = b >> 6, i0 = b & 63;
  const int w = tid >> 6, l = tid & 63;
  const int ph = w >> 1, pw = w & 1;
  const int e = l & 15, kg = l >> 4;

  // batched stage: 1584 = 6*256 + 48
  {
    short8 t[7]; int off[7]; bool vd[7];
#pragma unroll
    for (int it = 0; it < 7; ++it) {
      int i = tid + 256 * it;
      vd[it] = i < 1584;
      int ii = vd[it] ? i : 0;
      int r = ii / 528;
      int rem = ii - r * 528;
      int iwL = rem >> 3, li = rem & 7;
      int ih = i0 - 1 + r, iw = iwL - 1;
      off[it] = (r * 66 + iwL) * 72 + 8 * li;
      short8 v = {0, 0, 0, 0, 0, 0, 0, 0};
      if (vd[it] && (unsigned)ih < 64u && (unsigned)iw < 64u)
        v = *(const short8*)(zqT + (((long)(n * 64 + ih) * 64) + iw) * 64 + 8 * li);
      t[it] = v;
    }
#pragma unroll
    for (int it = 0; it < 7; ++it)
      if (vd[it]) *(short8*)&slab[off[it]] = t[it];
  }
  __syncthreads();

  f32x4 acc[4][4];
#pragma unroll
  for (int m = 0; m < 4; ++m)
#pragma unroll
    for (int nt = 0; nt < 4; ++nt) acc[m][nt] = (f32x4){0.f, 0.f, 0.f, 0.f};

  for (int ab = 0; ab < 4; ++ab) {
    const int rL = 1 + ph - (ab >> 1);
    const int coff = pw - (ab & 1) + 1;
#pragma unroll
    for (int ks = 0; ks < 2; ++ks) {
      short8 aF[4], bF[4];
#pragma unroll
      for (int m = 0; m < 4; ++m)
        aF[m] = *(const short8*)(AD1 + (((w * 4 + ab) * 64 + 16 * m + e) * 64) + 32 * ks + 8 * kg);
#pragma unroll
      for (int nt = 0; nt < 4; ++nt) {
        int iwL = nt * 16 + e + coff;
        bF[nt] = *(const short8*)&slab[(rL * 66 + iwL) * 72 + 32 * ks + 8 * kg];
      }
#pragma unroll
      for (int m = 0; m < 4; ++m)
#pragma unroll
        for (int nt = 0; nt < 4; ++nt)
          acc[m][nt] = MFMA16(aF[m], bF[nt], acc[m][nt]);
    }
  }

  __syncthreads();
#pragma unroll
  for (int m = 0; m < 4; ++m)
#pragma unroll
    for (int nt = 0; nt < 4; ++nt) {
      int owIdx = nt * 16 + e;
      int oc0 = 16 * m + 4 * kg;
      short4v o;
#pragma unroll
      for (int rr = 0; rr < 4; ++rr) {
        float v = acc[m][nt][rr] + sBias[oc0 + rr];
        o[rr] = f2bf(v > 0.f ? v : 0.f);
      }
      *(short4v*)&sOut[((w * 64 + owIdx) * 68) + oc0] = o;
    }
  __syncthreads();
  {
    const int oh = 2 * i0 + ph;
    const int ow = 2 * l + pw;
    short* dst = hT + (((long)(n * 128 + oh) * 128) + ow) * 64;
#pragma unroll
    for (int j = 0; j < 16; ++j) {
      short4v v = *(const short4v*)&sOut[((w * 64 + l) * 68) + 4 * j];
      *(short4v*)(dst + 4 * j) = v;
    }
  }
}

// ------------------------------ deconv2 (MFMA, parity, c-split dbuf) -------
// block: (n, q, wh). outputs oh = 4q..4q+3, ow = 128*wh..+127.
// wave = parity (ph,pw). M = 16 (3 real oc), K split: 2 passes x 32c x 4 taps.
// sIn[2][4 rows][66 iw][36c-pad] bf16 double-buffered; pass1 loads issued
// before pass0 MFMA (T14 overlap). sOut [3][4][128] f32 aliases buf0.
__global__ __launch_bounds__(256) void k_deconv2(const short* __restrict__ hT,
                                                 const short* __restrict__ AD2,
                                                 const float* __restrict__ db2,
                                                 float* __restrict__ xr) {
  __shared__ __align__(16) char smem[38016];   // 2 x 19008 B
  __shared__ float sB2[3];
  short* buf0 = (short*)smem;
  short* buf1 = (short*)(smem + 19008);
  float* sOut = (float*)smem;                  // [3][4][128] = 6144 B (buf0 alias)

  const int tid = threadIdx.x;
  if (tid < 3) sB2[tid] = db2[tid];
  const int b = blockIdx.x;
  const int n = b >> 7;
  const int rem0 = b & 127;
  const int q = rem0 >> 1, wh = rem0 & 1;
  const int w = tid >> 6, l = tid & 63;
  const int ph = w >> 1, pw = w & 1;
  const int e = l & 15, kg = l >> 4;

  // decode staging slots: 1056 lines = 4r x 66iw x 4li; 1056 = 4*256 + 32
  int soff[5]; long sga[5]; bool sv[5], sin[5];
#pragma unroll
  for (int it = 0; it < 5; ++it) {
    int i = tid + 256 * it;
    sv[it] = i < 1056;
    int ii = sv[it] ? i : 0;
    int r = ii / 264;
    int rm = ii - r * 264;
    int iwL = rm >> 2, li = rm & 3;
    int ih = 2 * q - 1 + r, iw = 64 * wh - 1 + iwL;
    sin[it] = sv[it] && (unsigned)ih < 128u && (unsigned)iw < 128u;
    soff[it] = (r * 66 + iwL) * 36 + 8 * li;
    sga[it] = (((long)(n * 128 + ih) * 128) + iw) * 64 + 8 * li;
  }

  // ---- stage pass 0 (c 0..31) into buf0
  {
    short8 t0[5];
#pragma unroll
    for (int it = 0; it < 5; ++it) {
      short8 v = {0, 0, 0, 0, 0, 0, 0, 0};
      if (sin[it]) v = *(const short8*)(hT + sga[it]);
      t0[it] = v;
    }
#pragma unroll
    for (int it = 0; it < 5; ++it)
      if (sv[it]) *(short8*)&buf0[soff[it]] = t0[it];
  }
  __syncthreads();

  // ---- issue pass-1 loads (c 32..63) before pass-0 compute
  short8 t1[5];
#pragma unroll
  for (int it = 0; it < 5; ++it) {
    short8 v = {0, 0, 0, 0, 0, 0, 0, 0};
    if (sin[it]) v = *(const short8*)(hT + sga[it] + 32);
    t1[it] = v;
  }

  f32x4 acc[2][4];
#pragma unroll
  for (int j = 0; j < 2; ++j)
#pragma unroll
    for (int nt = 0; nt < 4; ++nt) acc[j][nt] = (f32x4){0.f, 0.f, 0.f, 0.f};

  // ---- pass 0 MFMA
  {
    short8 aF[4];
#pragma unroll
    for (int ab = 0; ab < 4; ++ab)
      aF[ab] = *(const short8*)(AD2 + (((w * 4 + ab) * 16 + e) * 64) + 8 * kg);
#pragma unroll
    for (int ab = 0; ab < 4; ++ab) {
      const int a = ab >> 1, bb = ab & 1;
#pragma unroll
      for (int j = 0; j < 2; ++j) {
        const int rL = 1 + ph + j - a;
#pragma unroll
        for (int nt = 0; nt < 4; ++nt) {
          const int iwL = nt * 16 + e + pw - bb + 1;
          short8 bf = *(const short8*)&buf0[(rL * 66 + iwL) * 36 + 8 * kg];
          acc[j][nt] = MFMA16(aF[ab], bf, acc[j][nt]);
        }
      }
    }
  }

  // ---- write pass-1 data; barrier; pass-1 MFMA
#pragma unroll
  for (int it = 0; it < 5; ++it)
    if (sv[it]) *(short8*)&buf1[soff[it]] = t1[it];
  __syncthreads();

  {
    short8 aF[4];
#pragma unroll
    for (int ab = 0; ab < 4; ++ab)
      aF[ab] = *(const short8*)(AD2 + (((w * 4 + ab) * 16 + e) * 64) + 32 + 8 * kg);
#pragma unroll
    for (int ab = 0; ab < 4; ++ab) {
      const int a = ab >> 1, bb = ab & 1;
#pragma unroll
      for (int j = 0; j < 2; ++j) {
        const int rL = 1 + ph + j - a;
#pragma unroll
        for (int nt = 0; nt < 4; ++nt) {
          const int iwL = nt * 16 + e + pw - bb + 1;
          short8 bf = *(const short8*)&buf1[(rL * 66 + iwL) * 36 + 8 * kg];
          acc[j][nt] = MFMA16(aF[ab], bf, acc[j][nt]);
        }
      }
    }
  }

  // ---- epilogue: sigmoid on kg==0 lanes (rows oc 0..3 hold real oc 0..2)
  if (kg == 0) {
#pragma unroll
    for (int j = 0; j < 2; ++j)
#pragma unroll
      for (int nt = 0; nt < 4; ++nt) {
        int ohl = 2 * j + ph;
        int owl = 2 * (nt * 16 + e) + pw;
#pragma unroll
        for (int rr = 0; rr < 3; ++rr) {
          float v = 1.f / (1.f + expf(-(acc[j][nt][rr] + sB2[rr])));
          sOut[(rr * 4 + ohl) * 128 + owl] = v;
        }
      }
  }
  __syncthreads();
  // ---- coalesced store: 384 float4 (1536 floats)
#pragma unroll
  for (int it = 0; it < 2; ++it) {
    int i = tid + 256 * it;
    if (i < 384) {
      int oc = i >> 7, r2 = i & 127;
      int ohl = r2 >> 5, c4 = r2 & 31;
      float4 v = ((const float4*)sOut)[i];
      *(float4*)(xr + (((long)(n * 3 + oc) * 256) + 4 * q + ohl) * 256 + 128 * wh + 4 * c4) = v;
    }
  }
}

// ------------------------------ launch -------------------------------------
extern "C" void kernel_launch(void* const* d_in, const int* in_sizes, int n_in,
                              void* d_out, int out_size, void* d_ws, size_t ws_size,
                              hipStream_t stream) {
  (void)in_sizes; (void)n_in; (void)out_size; (void)ws_size;

  const float* x   = (const float*)d_in[0];
  const float* w1  = (const float*)d_in[1];
  const float* b1  = (const float*)d_in[2];
  const float* w2  = (const float*)d_in[3];
  const float* b2  = (const float*)d_in[4];
  const float* cb  = (const float*)d_in[5];
  const float* dw1 = (const float*)d_in[6];
  const float* db1 = (const float*)d_in[7];
  const float* dw2 = (const float*)d_in[8];
  const float* db2 = (const float*)d_in[9];

  char* wsb = (char*)d_ws;
  short* z1T = (short*)wsb;                        // 67,108,864 B (also hT)
  short* zeb = (short*)(wsb + 67108864);           // 16,777,216 B
  short* zqT = (short*)(wsb + 83886080);           // 16,777,216 B
  short* A2  = (short*)(wsb + 100663296);          //    131,072 B
  short* AD1 = (short*)(wsb + 100794368);          //    131,072 B
  short* cbb = (short*)(wsb + 100925440);          //     65,536 B
  float* cnm = (float*)(wsb + 100990976);          //      2,048 B
  short* AD2 = (short*)(wsb + 100993024);          //     32,768 B
  short* hT  = z1T;                                // alias (z1T dead after conv2)

  float* xr = (float*)d_out;                       // 6,291,456 f32
  float* zq = (float*)d_out + 6291456;             // 8,388,608 f32

  k_prep<<<256, 256, 0, stream>>>(w2, dw1, dw2, cb, A2, AD1, AD2, cbb, cnm);
  k_conv1<<<2048, 256, 0, stream>>>(x, w1, b1, z1T);
  k_conv2<<<1024, 256, 0, stream>>>(z1T, A2, b2, zeb);
  k_vq<<<2048, 256, 0, stream>>>(zeb, cbb, cnm, cb, zq, zqT);
  k_deconv1<<<2048, 256, 0, stream>>>(zqT, AD1, db1, hT);
  k_deconv2<<<4096, 256, 0, stream>>>(hT, AD2, db2, xr);
}